// Round 10
// baseline (211.048 us; speedup 1.0000x reference)
//
#include <hip/hip_runtime.h>
#include <hip/hip_bf16.h>

// Problem constants (B,S,E,H fixed by the reference)
#define BB 2
#define SS 2048
#define EE 1024
#define HH 16
#define DHH 64

using bf16x8 = __attribute__((ext_vector_type(8))) __bf16;
using f32x4  = __attribute__((ext_vector_type(4))) float;
using f32x16 = __attribute__((ext_vector_type(16))) float;
using uint2v = __attribute__((ext_vector_type(2))) unsigned int;

#if __has_builtin(__builtin_amdgcn_exp2f)
#define EXP2(x) __builtin_amdgcn_exp2f(x)
#else
#define EXP2(x) __exp2f(x)
#endif

// nkeep[b]: written by cvt_kernel's z=4 scan, read by proj GEMM early-exit.
__device__ int g_nkeep[2];

static __device__ __forceinline__ unsigned short f2bf(float f) {
    unsigned int u = __float_as_uint(f);
    u += 0x7FFFu + ((u >> 16) & 1u);   // round-to-nearest-even
    return (unsigned short)(u >> 16);
}

// pack two fp32 -> two bf16 in one uint (v_cvt_pk_bf16_f32 on gfx950)
static __device__ __forceinline__ unsigned int pk2bf(float lo, float hi) {
    union { __hip_bfloat162 h2; unsigned int u; } c;
    c.h2 = __float22bfloat162_rn(float2{lo, hi});
    return c.u;
}

// async global->LDS, 16B per lane; LDS dest = wave-uniform base + lane*16
static __device__ __forceinline__ void async_load16(const void* g, void* l) {
    __builtin_amdgcn_global_load_lds(
        (const __attribute__((address_space(1))) unsigned int*)g,
        (__attribute__((address_space(3))) unsigned int*)l, 16, 0, 0);
}

// ---------------------------------------------------------------------------
// cvt_kernel: weights (z 0..3) + mask scan (z=4) -> srcTab + g_nkeep.
// ---------------------------------------------------------------------------
__global__ void cvt_kernel(const float* __restrict__ W0, const float* __restrict__ W1,
                           const float* __restrict__ W2, const float* __restrict__ W3,
                           const int* __restrict__ mask,
                           unsigned short* __restrict__ Wb,
                           int* __restrict__ srcTab)
{
    const int z = blockIdx.y;
    if (z == 4) {
        // mask scan: one block per batch
        if (blockIdx.x >= 2) return;
        __shared__ int wsum[4];
        const int b    = blockIdx.x;
        const int tid  = threadIdx.x;
        const int lane = tid & 63;
        const int wave = tid >> 6;

        const int base = tid * 8;
        int v[8]; int run = 0;
        #pragma unroll
        for (int i = 0; i < 8; i++) { v[i] = (mask[b * SS + base + i] != 0) ? 1 : 0; run += v[i]; }

        int inc = run;
        #pragma unroll
        for (int d = 1; d < 64; d <<= 1) {
            int n = __shfl_up(inc, d, 64);
            if (lane >= d) inc += n;
        }
        if (lane == 63) wsum[wave] = inc;

        // clear all slots to -1 (pad marker)
        #pragma unroll
        for (int i = 0; i < 8; i++) srcTab[b * SS + base + i] = -1;
        __syncthreads();

        const int nkeep = wsum[0] + wsum[1] + wsum[2] + wsum[3];
        if (tid == 0) g_nkeep[b] = nkeep;

        int r = inc - run;                   // exclusive prefix
        #pragma unroll
        for (int w = 0; w < 4; w++) if (w < wave) r += wsum[w];
        #pragma unroll
        for (int i = 0; i < 8; i++) {
            if (v[i]) { srcTab[b * SS + r] = base + i; r++; }
        }
        return;
    }

    const float* src = (z == 0) ? W0 : (z == 1) ? W1 : (z == 2) ? W2 : W3;
    unsigned short* dst = Wb + (size_t)z * 1048576;
    const size_t base = (size_t)blockIdx.x * 2048 + (size_t)threadIdx.x * 8;
    const float4 f0 = *(const float4*)(src + base);
    const float4 f1 = *(const float4*)(src + base + 4);
    uint4 p;
    p.x = pk2bf(f0.x, f0.y); p.y = pk2bf(f0.z, f0.w);
    p.z = pk2bf(f1.x, f1.y); p.w = pk2bf(f1.z, f1.w);
    *(uint4*)(dst + base) = p;
}

// ---------------------------------------------------------------------------
// GEMM: Y[m][n] = sum_k A[m][k] * W[n][k]  (X @ W^T).
//
// R20 (this round): write-mid A-staging for AMODE=1. R9 measured the fused
// proj at 60us / MfmaUtil 10.3 -- the serial per-tile head
//   vmcnt(6) -> cvt+ds_write -> lgkmcnt(0) -> barrier -> compute
// put the A-write drain ON the barrier path (T14 mistake). New order:
//   stage(i+2) issue -> vmcnt(6) [tile i+1 regs ready] -> WRITE_A(i+1)
//   (fire-and-forget) -> compute(i) [MFMA overlaps write drain]
//   -> lgkmcnt(0) -> barrier
// WAR: WRITE_A(i+1) hits buf (i+1)%3; concurrent compute reads buf i%3;
// last read of (i+1)%3 was compute(i-2), two barriers back. vmcnt trace
// verified for prologue/steady/tail (niter=32 even, unroll-2, named sets).
//
//  AMODE=0 (out-GEMM): bf16 A via global_load_lds -- exact R8 path (proven).
//  AMODE=1 (proj GEMM): A direct from fp32 sources (queries / gathered
//    keys / values via srcTab), reg-cvt, ds_write-staged.
// Carried: T2 LDS swizzle both-sides, T4 counted-vmcnt, T1 XCD swizzle,
// z>0 early-exit beyond g_nkeep, z==2 V-proj transposed epilogue.
// ---------------------------------------------------------------------------
template<int MT, int NT, bool BF16OUT, int AMODE>
__global__ __launch_bounds__(256, 3)
void gemm_xwt(const unsigned short* __restrict__ Xb0, const unsigned short* __restrict__ Xb1,
              const unsigned short* __restrict__ Xb2,
              const float* __restrict__ Xf0, const float* __restrict__ Xf1,
              const float* __restrict__ Xf2, const int* __restrict__ srcTab,
              const unsigned short* __restrict__ W0, const unsigned short* __restrict__ W1,
              const unsigned short* __restrict__ W2,
              void* __restrict__ Y0, void* __restrict__ Y1, void* __restrict__ Y2,
              const float* __restrict__ bias, int M, int N, int K,
              float s0, float s1, float s2)
{
    constexpr int BK = 32;
    constexpr int NI = MT / 32;
    constexpr int NJ = NT / 32;
    __shared__ __align__(16) unsigned short As[3][MT * BK];
    __shared__ __align__(16) unsigned short Bs[3][NT * BK];

    const int z = blockIdx.z;
    const unsigned short* __restrict__ W = (z == 0) ? W0 : ((z == 1) ? W1 : W2);
    void* __restrict__ Y                 = (z == 0) ? Y0 : ((z == 1) ? Y1 : Y2);
    const float ysc                      = (z == 0) ? s0 : ((z == 1) ? s1 : s2);

    const int tid  = threadIdx.x;
    const int lane = tid & 63;
    const int wave = tid >> 6;
    const int wm   = (wave >> 1) * (MT / 2);
    const int wn   = (wave & 1) * (NT / 2);

    // T1 XCD-chunked swizzle (gridDim.y % 8 == 0 holds for all call sites)
    const unsigned gx  = gridDim.x;
    const unsigned gy  = gridDim.y;
    const unsigned lin = blockIdx.x + gx * blockIdx.y;
    const unsigned k8  = lin & 7u;
    const unsigned j   = lin >> 3;
    const int m0 = (int)(k8 * (gy >> 3) + j / gx) * MT;
    const int n0 = (int)(j % gx) * NT;

    // early-exit: compacted K/V proj tiles beyond nkeep (block-uniform)
    if (AMODE == 1 && z > 0) {
        const int bb = m0 >> 11;                // 2048 rows per batch
        if ((m0 & 2047) >= g_nkeep[bb]) return;
    }

    const int l16  = lane & 15;
    const int quad = lane >> 4;

    // staging geometry: lane covers row (lane>>2), chunk (lane&3) of 16 rows
    const int arow = lane >> 2;
    const int akc  = ((lane & 3) ^ ((lane >> 3) & 3)) * 8;   // B: swizzled gload src chunk
    const int rchunk = (quad ^ ((l16 >> 1) & 3)) * 8;        // read-side chunk (A and B)
    const int awc  = ((lane & 3) ^ ((arow >> 1) & 3)) * 8;   // A: swizzled ds_write chunk

    f32x4 acc[NI][NJ];
    #pragma unroll
    for (int i = 0; i < NI; i++)
        #pragma unroll
        for (int j2 = 0; j2 < NJ; j2++) acc[i][j2] = f32x4{0.f, 0.f, 0.f, 0.f};

    auto stageB = [&](int k0, int buf) {
        #pragma unroll
        for (int j2 = 0; j2 < NT / 64; j2++) {
            const int rr = wave * (NT / 4) + j2 * 16;
            async_load16(W + (size_t)(n0 + rr + arow) * K + k0 + akc, Bs[buf] + rr * BK);
        }
    };

    auto compute = [&](int buf) {
        bf16x8 afrag[NI], bfrag[NJ];
        #pragma unroll
        for (int ii = 0; ii < NI; ii++)
            afrag[ii] = *(const bf16x8*)(As[buf] + (wm + ii * 16 + l16) * BK + rchunk);
        #pragma unroll
        for (int j2 = 0; j2 < NJ; j2++)
            bfrag[j2] = *(const bf16x8*)(Bs[buf] + (wn + j2 * 16 + l16) * BK + rchunk);
        #pragma unroll
        for (int ii = 0; ii < NI; ii++)
            #pragma unroll
            for (int j2 = 0; j2 < NJ; j2++)
                acc[ii][j2] = __builtin_amdgcn_mfma_f32_16x16x32_bf16(afrag[ii], bfrag[j2], acc[ii][j2], 0, 0, 0);
    };

    const int niter = K / BK;                // 32

    if constexpr (AMODE == 0) {
        // ---- R8-proven path: A via gload_lds, counted-vmcnt 3-ring -------
        const unsigned short* __restrict__ X = (z == 0) ? Xb0 : ((z == 1) ? Xb1 : Xb2);
        auto stageA0 = [&](int k0, int buf) {
            #pragma unroll
            for (int j2 = 0; j2 < MT / 64; j2++) {
                const int rr = wave * (MT / 4) + j2 * 16;
                async_load16(X + (size_t)(m0 + rr + arow) * K + k0 + akc, As[buf] + rr * BK);
            }
        };
        stageB(0, 0); stageA0(0, 0);
        stageB(BK, 1); stageA0(BK, 1);
        int cur = 0;
        for (int i = 0; i < niter; i++) {
            if (i + 1 < niter) {
                // LPS = MT/64 + NT/64 (3 for 128x64)
                asm volatile("s_waitcnt vmcnt(3)" ::: "memory");
            } else {
                asm volatile("s_waitcnt vmcnt(0)" ::: "memory");
            }
            __builtin_amdgcn_s_barrier();
            if (i + 2 < niter) {
                const int nb = (cur >= 1) ? cur - 1 : 2;   // (cur+2)%3
                stageB((i + 2) * BK, nb); stageA0((i + 2) * BK, nb);
            }
            compute(cur);
            cur = (cur < 2) ? cur + 1 : 0;
        }
    } else {
        // ---- fused path: A = fp32 direct (+ gather for z>0), write-mid ---
        const float* __restrict__ XF = (z == 0) ? Xf0 : ((z == 1) ? Xf1 : Xf2);
        const int bb   = m0 >> 11;
        const int mloc = m0 & 2047;

        // per-thread A source pointers (k-independent, hoisted; srcTab loads
        // retire before any stage issues -> vmcnt stays pure)
        const float* aptr[2];
        bool azero[2];
        #pragma unroll
        for (int j2 = 0; j2 < 2; j2++) {
            const int rloc = wave * (MT / 4) + j2 * 16 + arow;
            int grow;
            if (z == 0) {
                grow = m0 + rloc; azero[j2] = false;
            } else {
                const int s = srcTab[bb * SS + mloc + rloc];
                azero[j2] = (s < 0);
                grow = bb * SS + (azero[j2] ? 0 : s);   // safe row keeps loads uniform
            }
            aptr[j2] = XF + (size_t)grow * K + (lane & 3) * 8;
        }

        float4 aS0[4], aS1[4];   // two NAMED reg sets (rule #20), [j2*2+half]
        #define STAGE_A(k0, S)                                                \
            { _Pragma("unroll")                                               \
              for (int j2 = 0; j2 < 2; j2++) {                                \
                  S[j2 * 2]     = *(const float4*)(aptr[j2] + (k0));          \
                  S[j2 * 2 + 1] = *(const float4*)(aptr[j2] + (k0) + 4);      \
              } }
        #define WRITE_A(buf, S)                                               \
            { _Pragma("unroll")                                               \
              for (int j2 = 0; j2 < 2; j2++) {                                \
                  uint4 w;                                                    \
                  w.x = pk2bf(S[j2*2].x, S[j2*2].y);                          \
                  w.y = pk2bf(S[j2*2].z, S[j2*2].w);                          \
                  w.z = pk2bf(S[j2*2+1].x, S[j2*2+1].y);                      \
                  w.w = pk2bf(S[j2*2+1].z, S[j2*2+1].w);                      \
                  if (azero[j2]) w = uint4{0, 0, 0, 0};                       \
                  const int rr = wave * (MT / 4) + j2 * 16 + arow;            \
                  *(uint4*)(As[buf] + rr * BK + awc) = w;                     \
              } }

        // prologue: stages 0,1 in flight; write tile 0, publish, barrier.
        stageB(0, 0);  STAGE_A(0, aS0);
        stageB(BK, 1); STAGE_A(BK, aS1);
        asm volatile("s_waitcnt vmcnt(6)" ::: "memory");   // stage 0 retired
        WRITE_A(0, aS0);
        asm volatile("s_waitcnt lgkmcnt(0)" ::: "memory");
        __builtin_amdgcn_s_barrier();                      // buf 0 ready

        for (int i = 0; i < niter; i += 2) {
            // ---- even tile i: compute buf i%3, write tile i+1, stage i+2 into aS0
            if (i + 2 < niter) {
                stageB((i + 2) * BK, (i + 2) % 3); STAGE_A((i + 2) * BK, aS0);
                asm volatile("s_waitcnt vmcnt(6)" ::: "memory");   // stage i+1 retired
            } else {
                asm volatile("s_waitcnt vmcnt(0)" ::: "memory");
            }
            if (i + 1 < niter) WRITE_A((i + 1) % 3, aS1);          // fire-and-forget
            compute(i % 3);                                        // overlaps write drain
            asm volatile("s_waitcnt lgkmcnt(0)" ::: "memory");
            __builtin_amdgcn_s_barrier();                          // buf i+1 ready

            // ---- odd tile i+1: compute buf (i+1)%3, write tile i+2, stage i+3 into aS1
            if (i + 3 < niter) {
                stageB((i + 3) * BK, (i + 3) % 3); STAGE_A((i + 3) * BK, aS1);
                asm volatile("s_waitcnt vmcnt(6)" ::: "memory");   // stage i+2 retired
            } else {
                asm volatile("s_waitcnt vmcnt(0)" ::: "memory");
            }
            if (i + 2 < niter) WRITE_A((i + 2) % 3, aS0);
            compute((i + 1) % 3);
            if (i + 2 < niter) {
                asm volatile("s_waitcnt lgkmcnt(0)" ::: "memory");
                __builtin_amdgcn_s_barrier();                      // buf i+2 ready
            }
        }
        #undef STAGE_A
        #undef WRITE_A
    }

    // Epilogue. C/D layout: col = lane&15, row = quad*4 + reg.
    if (BF16OUT && z == 2) {
        // V proj: store transposed -> Vtc[(b*EE + col)*SS + slot].
        #pragma unroll
        for (int i = 0; i < NI; i++) {
            #pragma unroll
            for (int j2 = 0; j2 < NJ; j2++) {
                const int row  = m0 + wm + i * 16 + quad * 4;
                const int bb2  = row >> 11;
                const int slot = row & 2047;
                const int col  = n0 + wn + j2 * 16 + l16;
                uint2 pck;
                pck.x = pk2bf(acc[i][j2][0], acc[i][j2][1]);
                pck.y = pk2bf(acc[i][j2][2], acc[i][j2][3]);
                *(uint2*)((unsigned short*)Y + ((size_t)(bb2 * EE + col)) * SS + slot) = pck;
            }
        }
    } else {
        #pragma unroll
        for (int i = 0; i < NI; i++) {
            #pragma unroll
            for (int j2 = 0; j2 < NJ; j2++) {
                #pragma unroll
                for (int r = 0; r < 4; r++) {
                    const int row = m0 + wm + i * 16 + quad * 4 + r;
                    const int col = n0 + wn + j2 * 16 + l16;
                    const float v = acc[i][j2][r];
                    if (BF16OUT) {
                        ((unsigned short*)Y)[(size_t)row * N + col] = f2bf(v * ysc);
                    } else {
                        ((float*)Y)[(size_t)row * N + col] = v + bias[col];
                    }
                }
            }
        }
    }
}

// ---------------------------------------------------------------------------
// Flash attention v13 (unchanged, proven): 32x32x16 MFMA, swapped QK^T,
// in-register softmax via cvt_pk + permlane32_swap (T12), s_setprio (T5).
// ---------------------------------------------------------------------------
__global__ __launch_bounds__(256, 2)
void attn_kernel(const unsigned short* __restrict__ Qb,
                 const unsigned short* __restrict__ Kc,
                 const unsigned short* __restrict__ Vtc,
                 const int* __restrict__ mask,
                 unsigned short* __restrict__ AO)
{
    constexpr int LDK = 68;
    constexpr int LDV = 68;
    __shared__ __align__(16) unsigned short Ks[64 * LDK];   // [key][d]
    __shared__ __align__(16) unsigned short Vs[64 * LDV];   // [d][key]
    __shared__ float Lsum[4][32];
    __shared__ int nk_s;

    const int tid  = threadIdx.x;
    const int lane = tid & 63;
    const int wave = tid >> 6;
    const int l32  = lane & 31;
    const int hi   = lane >> 5;

    const int linear = blockIdx.x;
    const int bh     = (linear & 7) * 4 + ((linear >> 3) & 3);
    const int qblk   = linear >> 5;
    const int b  = bh >> 4;
    const int h  = bh & 15;
    const int q0 = qblk * 128 + wave * 32;

    if (tid == 0) nk_s = 0;
    __syncthreads();
    {
        int cnt = 0;
        #pragma unroll
        for (int i = 0; i < 8; i++) cnt += (mask[b * SS + tid * 8 + i] != 0) ? 1 : 0;
        #pragma unroll
        for (int d = 32; d >= 1; d >>= 1) cnt += __shfl_xor(cnt, d, 64);
        if (lane == 0) atomicAdd(&nk_s, cnt);
    }
    __syncthreads();
    const int nkeep  = nk_s;
    const int ntiles = (nkeep + 63) >> 6;

    bf16x8 qf[4];
    {
        const unsigned short* qptr = Qb + (size_t)(b * SS + q0 + l32) * EE + h * DHH + hi * 8;
        #pragma unroll
        for (int t = 0; t < 4; t++) qf[t] = *(const bf16x8*)(qptr + t * 16);
    }

    float lsum = 0.f;
    f32x16 o_acc[2];
    #pragma unroll
    for (int d = 0; d < 2; d++)
        #pragma unroll
        for (int r = 0; r < 16; r++) o_acc[d][r] = 0.f;

    const int srow = tid >> 2;
    const int sc   = (tid & 3) * 16;

    uint4 kr0, kr1, vr0, vr1;
    auto gload = [&](int t0) {
        const unsigned short* kg = Kc + (size_t)(b * SS + t0 + srow) * EE + h * DHH + sc;
        kr0 = *(const uint4*)(kg);
        kr1 = *(const uint4*)(kg + 8);
        const unsigned short* vg = Vtc + (size_t)(b * EE + h * DHH + srow) * SS + t0 + sc;
        vr0 = *(const uint4*)(vg);
        vr1 = *(const uint4*)(vg + 8);
    };
    gload(0);

    for (int it = 0; it < ntiles; it++) {
        const int t0 = it * 64;
        __syncthreads();
        *(uint4*)(Ks + srow * LDK + sc)     = kr0;
        *(uint4*)(Ks + srow * LDK + sc + 8) = kr1;
        *(uint4*)(Vs + srow * LDV + sc)     = vr0;
        *(uint4*)(Vs + srow * LDV + sc + 8) = vr1;
        __syncthreads();

        if (it + 1 < ntiles) gload(t0 + 64);

        const bool full = (t0 + 64 <= nkeep);

        #pragma unroll
        for (int blk = 0; blk < 2; blk++) {
            f32x16 s;
            __builtin_amdgcn_s_setprio(1);
            {
                bf16x8 kf = *(const bf16x8*)(Ks + (blk * 32 + l32) * LDK + hi * 8);
                f32x16 z;
                #pragma unroll
                for (int r = 0; r < 16; r++) z[r] = 0.f;
                s = __builtin_amdgcn_mfma_f32_32x32x16_bf16(kf, qf[0], z, 0, 0, 0);
            }
            #pragma unroll
            for (int t = 1; t < 4; t++) {
                bf16x8 kf = *(const bf16x8*)(Ks + (blk * 32 + l32) * LDK + t * 16 + hi * 8);
                s = __builtin_amdgcn_mfma_f32_32x32x16_bf16(kf, qf[t], s, 0, 0, 0);
            }
            __builtin_amdgcn_s_setprio(0);

            float p[16];
            #pragma unroll
            for (int r = 0; r < 16; r++) p[r] = EXP2(s[r]);
            if (!full) {
                const int keyb = t0 + blk * 32 + 4 * hi;
                #pragma unroll
                for (int r = 0; r < 16; r++)
                    if (keyb + ((r & 3) + 8 * (r >> 2)) >= nkeep) p[r] = 0.f;
            }
            #pragma unroll
            for (int r = 0; r < 16; r += 4)
                lsum += ((p[r] + p[r + 1]) + (p[r + 2] + p[r + 3]));

            const unsigned int u0 = pk2bf(p[0],  p[1]);
            const unsigned int u1 = pk2bf(p[2],  p[3]);
            const unsigned int u2 = pk2bf(p[4],  p[5]);
            const unsigned int u3 = pk2bf(p[6],  p[7]);
            const unsigned int u4 = pk2bf(p[8],  p[9]);
            const unsigned int u5 = pk2bf(p[10], p[11]);
            const unsigned int u6 = pk2bf(p[12], p[13]);
            const unsigned int u7 = pk2bf(p[14], p[15]);
            const uint2v s02 = __builtin_amdgcn_permlane32_swap(u0, u2, false, false);
            const uint2v s13 = __builtin_amdgcn_permlane32_swap(u1, u3, false, false);
            const uint2v s46 = __builtin_amdgcn_permlane32_swap(u4, u6, false, false);
            const uint2v s57 = __builtin_amdgcn_permlane32_swap(u5, u7, false, false);

            union { unsigned int u[4]; bf16x8 v; } pa0, pa1;
            pa0.u[0] = s02.x; pa0.u[1] = s13.x; pa0.u[2] = s02.y; pa0.u[3] = s13.y;
            pa1.u[0] = s46.x; pa1.u[1] = s57.x; pa1.u[2] = s46.y; pa1.u[3] = s57.y;

            __builtin_amdgcn_s_setprio(1);
            #pragma unroll
            for (int kc = 0; kc < 2; kc++) {
                const bf16x8 pav = (kc == 0) ? pa0.v : pa1.v;
                #pragma unroll
                for (int dblk = 0; dblk < 2; dblk++) {
                    bf16x8 vf = *(const bf16x8*)(Vs + (dblk * 32 + l32) * LDV + blk * 32 + kc * 16 + hi * 8);
                    o_acc[dblk] = __builtin_amdgcn_mfma_f32_32x32x16_bf16(pav, vf, o_acc[dblk], 0, 0, 0);
                }
            }
            __builtin_amdgcn_s_setprio(0);
        }
    }

    {
        float ls = lsum;
        ls += __shfl_xor(ls, 32, 64);
        Lsum[wave][l32] = 1.0f / ls;
    }
    __builtin_amdgcn_s_waitcnt(0xC07F);

    #pragma unroll
    for (int r = 0; r < 16; r++) {
        const int qr = (r & 3) + 8 * (r >> 2) + 4 * hi;
        const float rl = Lsum[wave][qr];
        const size_t orow = (size_t)(b * SS + q0 + qr) * EE + h * DHH + l32;
        AO[orow]      = f2bf(o_acc[0][r] * rl);
        AO[orow + 32] = f2bf(o_acc[1][r] * rl);
    }
}

// ---------------------------------------------------------------------------
// Aliasing plan:
//   ws (40 MB):  [Wb 8 | Qb 8 | Kc 8 | Vtc 8 | AOb 8]
//   d_out: srcTab (16 KB) scratch -- dead before the out-GEMM overwrites.
// Pipeline (4 launches): cvt(weights+scan) -> proj GEMM (fused cvt+gather,
// V transposed epilogue) -> attn -> out GEMM.
// ---------------------------------------------------------------------------
extern "C" void kernel_launch(void* const* d_in, const int* in_sizes, int n_in,
                              void* d_out, int out_size, void* d_ws, size_t ws_size,
                              hipStream_t stream)
{
    (void)in_sizes; (void)n_in; (void)out_size; (void)ws_size;
    const float* queries = (const float*)d_in[0];
    const float* keys    = (const float*)d_in[1];
    const float* values  = (const float*)d_in[2];
    const int*   mask    = (const int*)d_in[3];
    const float* Wq      = (const float*)d_in[4];
    const float* Wk      = (const float*)d_in[5];
    const float* Wv      = (const float*)d_in[6];
    const float* Wo      = (const float*)d_in[7];
    const float* bo      = (const float*)d_in[8];

    const size_t NE = (size_t)BB * SS * EE;          // 4.19M elements
    const size_t WE = (size_t)EE * EE;               // 1.05M elements

    unsigned short* Wb  = (unsigned short*)d_ws;     // [0,8) MB
    unsigned short* Qb  = Wb + 4 * WE;               // [8,16)
    unsigned short* Kc  = Qb + NE;                   // [16,24)
    unsigned short* Vtc = Kc + NE;                   // [24,32)
    unsigned short* AOb = Vtc + NE;                  // [32,40)

    int* srcTab = (int*)d_out;                       // 16 KB scratch (dead by out-GEMM)

    const int M = BB * SS, N = EE, K = EE;
    // 1/sqrt(2048) * log2(e): softmax exp computed as exp2 of pre-scaled score
    const float qscale = 0.022097086912079608f * 1.4426950408889634f;

    cvt_kernel<<<dim3(512, 5), 256, 0, stream>>>(
        Wq, Wk, Wv, Wo, mask, Wb, srcTab);

    dim3 gproj(N / 128, M / 128, 3);
    gemm_xwt<128, 128, true, 1><<<gproj, 256, 0, stream>>>(
        nullptr, nullptr, nullptr,
        queries, keys, values, srcTab,
        Wb, Wb + WE, Wb + 2 * WE,
        (void*)Qb, (void*)Kc, (void*)Vtc, nullptr, M, N, K,
        qscale, 1.0f, 1.0f);

    attn_kernel<<<dim3(512), 256, 0, stream>>>(Qb, Kc, Vtc, mask, AOb);

    dim3 gout(N / 64, M / 128, 1);
    gemm_xwt<128, 64, false, 0><<<gout, 256, 0, stream>>>(
        AOb, AOb, AOb,
        nullptr, nullptr, nullptr, nullptr,
        Wb + 3 * WE, Wb + 3 * WE, Wb + 3 * WE,
        d_out, d_out, d_out, bo, M, N, K, 1.0f, 1.0f, 1.0f);
}

// Round 11
// 203.409 us; speedup vs baseline: 1.0376x; 1.0376x over previous
//
#include <hip/hip_runtime.h>
#include <hip/hip_bf16.h>

// Problem constants (B,S,E,H fixed by the reference)
#define BB 2
#define SS 2048
#define EE 1024
#define HH 16
#define DHH 64

using bf16x8 = __attribute__((ext_vector_type(8))) __bf16;
using f32x4  = __attribute__((ext_vector_type(4))) float;
using f32x16 = __attribute__((ext_vector_type(16))) float;
using uint2v = __attribute__((ext_vector_type(2))) unsigned int;

#if __has_builtin(__builtin_amdgcn_exp2f)
#define EXP2(x) __builtin_amdgcn_exp2f(x)
#else
#define EXP2(x) __exp2f(x)
#endif

// nkeep[b]: written by cvt_kernel's z=4 scan, read by proj GEMM early-exit.
__device__ int g_nkeep[2];

static __device__ __forceinline__ unsigned short f2bf(float f) {
    unsigned int u = __float_as_uint(f);
    u += 0x7FFFu + ((u >> 16) & 1u);   // round-to-nearest-even
    return (unsigned short)(u >> 16);
}

// pack two fp32 -> two bf16 in one uint (v_cvt_pk_bf16_f32 on gfx950)
static __device__ __forceinline__ unsigned int pk2bf(float lo, float hi) {
    union { __hip_bfloat162 h2; unsigned int u; } c;
    c.h2 = __float22bfloat162_rn(float2{lo, hi});
    return c.u;
}

// async global->LDS, 16B per lane; LDS dest = wave-uniform base + lane*16
static __device__ __forceinline__ void async_load16(const void* g, void* l) {
    __builtin_amdgcn_global_load_lds(
        (const __attribute__((address_space(1))) unsigned int*)g,
        (__attribute__((address_space(3))) unsigned int*)l, 16, 0, 0);
}

// ---------------------------------------------------------------------------
// cvt_kernel: weights (z 0..3) + mask scan (z=4) -> srcTab + g_nkeep.
// ---------------------------------------------------------------------------
__global__ void cvt_kernel(const float* __restrict__ W0, const float* __restrict__ W1,
                           const float* __restrict__ W2, const float* __restrict__ W3,
                           const int* __restrict__ mask,
                           unsigned short* __restrict__ Wb,
                           int* __restrict__ srcTab)
{
    const int z = blockIdx.y;
    if (z == 4) {
        // mask scan: one block per batch
        if (blockIdx.x >= 2) return;
        __shared__ int wsum[4];
        const int b    = blockIdx.x;
        const int tid  = threadIdx.x;
        const int lane = tid & 63;
        const int wave = tid >> 6;

        const int base = tid * 8;
        int v[8]; int run = 0;
        #pragma unroll
        for (int i = 0; i < 8; i++) { v[i] = (mask[b * SS + base + i] != 0) ? 1 : 0; run += v[i]; }

        int inc = run;
        #pragma unroll
        for (int d = 1; d < 64; d <<= 1) {
            int n = __shfl_up(inc, d, 64);
            if (lane >= d) inc += n;
        }
        if (lane == 63) wsum[wave] = inc;

        // clear all slots to -1 (pad marker)
        #pragma unroll
        for (int i = 0; i < 8; i++) srcTab[b * SS + base + i] = -1;
        __syncthreads();

        const int nkeep = wsum[0] + wsum[1] + wsum[2] + wsum[3];
        if (tid == 0) g_nkeep[b] = nkeep;

        int r = inc - run;                   // exclusive prefix
        #pragma unroll
        for (int w = 0; w < 4; w++) if (w < wave) r += wsum[w];
        #pragma unroll
        for (int i = 0; i < 8; i++) {
            if (v[i]) { srcTab[b * SS + r] = base + i; r++; }
        }
        return;
    }

    const float* src = (z == 0) ? W0 : (z == 1) ? W1 : (z == 2) ? W2 : W3;
    unsigned short* dst = Wb + (size_t)z * 1048576;
    const size_t base = (size_t)blockIdx.x * 2048 + (size_t)threadIdx.x * 8;
    const float4 f0 = *(const float4*)(src + base);
    const float4 f1 = *(const float4*)(src + base + 4);
    uint4 p;
    p.x = pk2bf(f0.x, f0.y); p.y = pk2bf(f0.z, f0.w);
    p.z = pk2bf(f1.x, f1.y); p.w = pk2bf(f1.z, f1.w);
    *(uint4*)(dst + base) = p;
}

// ---------------------------------------------------------------------------
// GEMM: Y[m][n] = sum_k A[m][k] * W[n][k]  (X @ W^T).
//
// R21: write-after-barrier pipeline with deep A-prefetch for AMODE=1.
// R10 post-mortem: moving stage-issue to the iter top cut prefetch cover
// from 2 phases to 1 -> vmcnt(6) stalled every iter (+5us). R21 keeps the
// write OFF the barrier path AND restores cover via FIFO-coupled waits:
//   [barrier] -> WRITE_A(i+1)  (A(i+1) already retired by prev vmcnt(6))
//             -> STAGE_A(i+3) -> stageB(i+2)
//             -> compute(i)   (covers the ds_write drain)
//             -> lgkmcnt(0) (free) -> vmcnt(6) (A(i+2)+B(i+1), ~1.7 phases old)
//             -> barrier
// Queue trace verified: steady invariant 6 outstanding at iter entry
// (A(i+2)[4] + B(i+1)[2]); prologue A0,A1,B0 -> vmcnt(6) -> W(0) -> A2,B1
// -> vmcnt(6); tail (i>=niter-3) uses vmcnt(0). Ring: WRITE (i+1)%3,
// compute i%3, prior reads (i-1)%3 all distinct mod 3; stageB(i+2) vs
// Bs[i%3] distinct.
//
//  AMODE=0 (out-GEMM): bf16 A via global_load_lds -- exact R8 path (proven).
//  AMODE=1 (proj GEMM): A direct from fp32 sources (queries / gathered
//    keys / values via srcTab), reg-cvt, ds_write-staged.
// Carried: T2 LDS swizzle both-sides, T4 counted-vmcnt, T1 XCD swizzle,
// z>0 early-exit beyond g_nkeep, z==2 V-proj transposed epilogue.
// ---------------------------------------------------------------------------
template<int MT, int NT, bool BF16OUT, int AMODE>
__global__ __launch_bounds__(256, 3)
void gemm_xwt(const unsigned short* __restrict__ Xb0, const unsigned short* __restrict__ Xb1,
              const unsigned short* __restrict__ Xb2,
              const float* __restrict__ Xf0, const float* __restrict__ Xf1,
              const float* __restrict__ Xf2, const int* __restrict__ srcTab,
              const unsigned short* __restrict__ W0, const unsigned short* __restrict__ W1,
              const unsigned short* __restrict__ W2,
              void* __restrict__ Y0, void* __restrict__ Y1, void* __restrict__ Y2,
              const float* __restrict__ bias, int M, int N, int K,
              float s0, float s1, float s2)
{
    constexpr int BK = 32;
    constexpr int NI = MT / 32;
    constexpr int NJ = NT / 32;
    __shared__ __align__(16) unsigned short As[3][MT * BK];
    __shared__ __align__(16) unsigned short Bs[3][NT * BK];

    const int z = blockIdx.z;
    const unsigned short* __restrict__ W = (z == 0) ? W0 : ((z == 1) ? W1 : W2);
    void* __restrict__ Y                 = (z == 0) ? Y0 : ((z == 1) ? Y1 : Y2);
    const float ysc                      = (z == 0) ? s0 : ((z == 1) ? s1 : s2);

    const int tid  = threadIdx.x;
    const int lane = tid & 63;
    const int wave = tid >> 6;
    const int wm   = (wave >> 1) * (MT / 2);
    const int wn   = (wave & 1) * (NT / 2);

    // T1 XCD-chunked swizzle (gridDim.y % 8 == 0 holds for all call sites)
    const unsigned gx  = gridDim.x;
    const unsigned gy  = gridDim.y;
    const unsigned lin = blockIdx.x + gx * blockIdx.y;
    const unsigned k8  = lin & 7u;
    const unsigned j   = lin >> 3;
    const int m0 = (int)(k8 * (gy >> 3) + j / gx) * MT;
    const int n0 = (int)(j % gx) * NT;

    // early-exit: compacted K/V proj tiles beyond nkeep (block-uniform)
    if (AMODE == 1 && z > 0) {
        const int bb = m0 >> 11;                // 2048 rows per batch
        if ((m0 & 2047) >= g_nkeep[bb]) return;
    }

    const int l16  = lane & 15;
    const int quad = lane >> 4;

    // staging geometry: lane covers row (lane>>2), chunk (lane&3) of 16 rows
    const int arow = lane >> 2;
    const int akc  = ((lane & 3) ^ ((lane >> 3) & 3)) * 8;   // B: swizzled gload src chunk
    const int rchunk = (quad ^ ((l16 >> 1) & 3)) * 8;        // read-side chunk (A and B)
    const int awc  = ((lane & 3) ^ ((arow >> 1) & 3)) * 8;   // A: swizzled ds_write chunk

    f32x4 acc[NI][NJ];
    #pragma unroll
    for (int i = 0; i < NI; i++)
        #pragma unroll
        for (int j2 = 0; j2 < NJ; j2++) acc[i][j2] = f32x4{0.f, 0.f, 0.f, 0.f};

    auto stageB = [&](int k0, int buf) {
        #pragma unroll
        for (int j2 = 0; j2 < NT / 64; j2++) {
            const int rr = wave * (NT / 4) + j2 * 16;
            async_load16(W + (size_t)(n0 + rr + arow) * K + k0 + akc, Bs[buf] + rr * BK);
        }
    };

    auto compute = [&](int buf) {
        bf16x8 afrag[NI], bfrag[NJ];
        #pragma unroll
        for (int ii = 0; ii < NI; ii++)
            afrag[ii] = *(const bf16x8*)(As[buf] + (wm + ii * 16 + l16) * BK + rchunk);
        #pragma unroll
        for (int j2 = 0; j2 < NJ; j2++)
            bfrag[j2] = *(const bf16x8*)(Bs[buf] + (wn + j2 * 16 + l16) * BK + rchunk);
        #pragma unroll
        for (int ii = 0; ii < NI; ii++)
            #pragma unroll
            for (int j2 = 0; j2 < NJ; j2++)
                acc[ii][j2] = __builtin_amdgcn_mfma_f32_16x16x32_bf16(afrag[ii], bfrag[j2], acc[ii][j2], 0, 0, 0);
    };

    const int niter = K / BK;                // 32

    if constexpr (AMODE == 0) {
        // ---- R8-proven path: A via gload_lds, counted-vmcnt 3-ring -------
        const unsigned short* __restrict__ X = (z == 0) ? Xb0 : ((z == 1) ? Xb1 : Xb2);
        auto stageA0 = [&](int k0, int buf) {
            #pragma unroll
            for (int j2 = 0; j2 < MT / 64; j2++) {
                const int rr = wave * (MT / 4) + j2 * 16;
                async_load16(X + (size_t)(m0 + rr + arow) * K + k0 + akc, As[buf] + rr * BK);
            }
        };
        stageB(0, 0); stageA0(0, 0);
        stageB(BK, 1); stageA0(BK, 1);
        int cur = 0;
        for (int i = 0; i < niter; i++) {
            if (i + 1 < niter) {
                // LPS = MT/64 + NT/64 (3 for 128x64)
                asm volatile("s_waitcnt vmcnt(3)" ::: "memory");
            } else {
                asm volatile("s_waitcnt vmcnt(0)" ::: "memory");
            }
            __builtin_amdgcn_s_barrier();
            if (i + 2 < niter) {
                const int nb = (cur >= 1) ? cur - 1 : 2;   // (cur+2)%3
                stageB((i + 2) * BK, nb); stageA0((i + 2) * BK, nb);
            }
            compute(cur);
            cur = (cur < 2) ? cur + 1 : 0;
        }
    } else {
        // ---- fused path: A fp32 direct (+ gather), write-after-barrier ---
        const float* __restrict__ XF = (z == 0) ? Xf0 : ((z == 1) ? Xf1 : Xf2);
        const int bb   = m0 >> 11;
        const int mloc = m0 & 2047;

        // per-thread A source pointers (k-independent, hoisted; srcTab loads
        // retire before any stage issues -> vmcnt stays pure)
        const float* aptr[2];
        bool azero[2];
        #pragma unroll
        for (int j2 = 0; j2 < 2; j2++) {
            const int rloc = wave * (MT / 4) + j2 * 16 + arow;
            int grow;
            if (z == 0) {
                grow = m0 + rloc; azero[j2] = false;
            } else {
                const int s = srcTab[bb * SS + mloc + rloc];
                azero[j2] = (s < 0);
                grow = bb * SS + (azero[j2] ? 0 : s);   // safe row keeps loads uniform
            }
            aptr[j2] = XF + (size_t)grow * K + (lane & 3) * 8;
        }

        float4 aS0[4], aS1[4];   // two NAMED reg sets (rule #20), [j2*2+half]
        #define STAGE_A(k0, S)                                                \
            { _Pragma("unroll")                                               \
              for (int j2 = 0; j2 < 2; j2++) {                                \
                  S[j2 * 2]     = *(const float4*)(aptr[j2] + (k0));          \
                  S[j2 * 2 + 1] = *(const float4*)(aptr[j2] + (k0) + 4);      \
              } }
        #define WRITE_A(buf, S)                                               \
            { _Pragma("unroll")                                               \
              for (int j2 = 0; j2 < 2; j2++) {                                \
                  uint4 w;                                                    \
                  w.x = pk2bf(S[j2*2].x, S[j2*2].y);                          \
                  w.y = pk2bf(S[j2*2].z, S[j2*2].w);                          \
                  w.z = pk2bf(S[j2*2+1].x, S[j2*2+1].y);                      \
                  w.w = pk2bf(S[j2*2+1].z, S[j2*2+1].w);                      \
                  if (azero[j2]) w = uint4{0, 0, 0, 0};                       \
                  const int rr = wave * (MT / 4) + j2 * 16 + arow;            \
                  *(uint4*)(As[buf] + rr * BK + awc) = w;                     \
              } }

        // prologue: queue A0(4),A1(4),B0(2) -> vmcnt(6) retires A0.
        STAGE_A(0, aS0);
        STAGE_A(BK, aS1);
        stageB(0, 0);
        asm volatile("s_waitcnt vmcnt(6)" ::: "memory");   // A(0) ready
        WRITE_A(0, aS0);
        STAGE_A(2 * BK, aS0);                              // A(2)
        stageB(BK, 1);                                     // B(1)
        asm volatile("s_waitcnt lgkmcnt(0)" ::: "memory"); // A(0) writes drained
        asm volatile("s_waitcnt vmcnt(6)" ::: "memory");   // retires A(1),B(0)
        __builtin_amdgcn_s_barrier();                      // buf 0 ready

        for (int i = 0; i < niter; i += 2) {
            // ---- even tile i: write i+1 (aS1), stage A(i+3)->aS1, B(i+2)
            if (i + 1 < niter) WRITE_A((i + 1) % 3, aS1);  // no wait: A(i+1) retired
            if (i + 3 < niter) STAGE_A((i + 3) * BK, aS1);
            if (i + 2 < niter) stageB((i + 2) * BK, (i + 2) % 3);
            compute(i % 3);                                // covers write drain
            asm volatile("s_waitcnt lgkmcnt(0)" ::: "memory");
            if (i + 3 < niter) asm volatile("s_waitcnt vmcnt(6)" ::: "memory");
            else               asm volatile("s_waitcnt vmcnt(0)" ::: "memory");
            __builtin_amdgcn_s_barrier();                  // buf i+1 ready

            // ---- odd tile i+1: write i+2 (aS0), stage A(i+4)->aS0, B(i+3)
            if (i + 2 < niter) WRITE_A((i + 2) % 3, aS0);
            if (i + 4 < niter) STAGE_A((i + 4) * BK, aS0);
            if (i + 3 < niter) stageB((i + 3) * BK, (i + 3) % 3);
            compute((i + 1) % 3);
            if (i + 2 < niter) {
                asm volatile("s_waitcnt lgkmcnt(0)" ::: "memory");
                if (i + 4 < niter) asm volatile("s_waitcnt vmcnt(6)" ::: "memory");
                else               asm volatile("s_waitcnt vmcnt(0)" ::: "memory");
                __builtin_amdgcn_s_barrier();              // buf i+2 ready
            }
        }
        #undef STAGE_A
        #undef WRITE_A
    }

    // Epilogue. C/D layout: col = lane&15, row = quad*4 + reg.
    if (BF16OUT && z == 2) {
        // V proj: store transposed -> Vtc[(b*EE + col)*SS + slot].
        #pragma unroll
        for (int i = 0; i < NI; i++) {
            #pragma unroll
            for (int j2 = 0; j2 < NJ; j2++) {
                const int row  = m0 + wm + i * 16 + quad * 4;
                const int bb2  = row >> 11;
                const int slot = row & 2047;
                const int col  = n0 + wn + j2 * 16 + l16;
                uint2 pck;
                pck.x = pk2bf(acc[i][j2][0], acc[i][j2][1]);
                pck.y = pk2bf(acc[i][j2][2], acc[i][j2][3]);
                *(uint2*)((unsigned short*)Y + ((size_t)(bb2 * EE + col)) * SS + slot) = pck;
            }
        }
    } else {
        #pragma unroll
        for (int i = 0; i < NI; i++) {
            #pragma unroll
            for (int j2 = 0; j2 < NJ; j2++) {
                #pragma unroll
                for (int r = 0; r < 4; r++) {
                    const int row = m0 + wm + i * 16 + quad * 4 + r;
                    const int col = n0 + wn + j2 * 16 + l16;
                    const float v = acc[i][j2][r];
                    if (BF16OUT) {
                        ((unsigned short*)Y)[(size_t)row * N + col] = f2bf(v * ysc);
                    } else {
                        ((float*)Y)[(size_t)row * N + col] = v + bias[col];
                    }
                }
            }
        }
    }
}

// ---------------------------------------------------------------------------
// Flash attention v13 (unchanged, proven): 32x32x16 MFMA, swapped QK^T,
// in-register softmax via cvt_pk + permlane32_swap (T12), s_setprio (T5).
// ---------------------------------------------------------------------------
__global__ __launch_bounds__(256, 2)
void attn_kernel(const unsigned short* __restrict__ Qb,
                 const unsigned short* __restrict__ Kc,
                 const unsigned short* __restrict__ Vtc,
                 const int* __restrict__ mask,
                 unsigned short* __restrict__ AO)
{
    constexpr int LDK = 68;
    constexpr int LDV = 68;
    __shared__ __align__(16) unsigned short Ks[64 * LDK];   // [key][d]
    __shared__ __align__(16) unsigned short Vs[64 * LDV];   // [d][key]
    __shared__ float Lsum[4][32];
    __shared__ int nk_s;

    const int tid  = threadIdx.x;
    const int lane = tid & 63;
    const int wave = tid >> 6;
    const int l32  = lane & 31;
    const int hi   = lane >> 5;

    const int linear = blockIdx.x;
    const int bh     = (linear & 7) * 4 + ((linear >> 3) & 3);
    const int qblk   = linear >> 5;
    const int b  = bh >> 4;
    const int h  = bh & 15;
    const int q0 = qblk * 128 + wave * 32;

    if (tid == 0) nk_s = 0;
    __syncthreads();
    {
        int cnt = 0;
        #pragma unroll
        for (int i = 0; i < 8; i++) cnt += (mask[b * SS + tid * 8 + i] != 0) ? 1 : 0;
        #pragma unroll
        for (int d = 32; d >= 1; d >>= 1) cnt += __shfl_xor(cnt, d, 64);
        if (lane == 0) atomicAdd(&nk_s, cnt);
    }
    __syncthreads();
    const int nkeep  = nk_s;
    const int ntiles = (nkeep + 63) >> 6;

    bf16x8 qf[4];
    {
        const unsigned short* qptr = Qb + (size_t)(b * SS + q0 + l32) * EE + h * DHH + hi * 8;
        #pragma unroll
        for (int t = 0; t < 4; t++) qf[t] = *(const bf16x8*)(qptr + t * 16);
    }

    float lsum = 0.f;
    f32x16 o_acc[2];
    #pragma unroll
    for (int d = 0; d < 2; d++)
        #pragma unroll
        for (int r = 0; r < 16; r++) o_acc[d][r] = 0.f;

    const int srow = tid >> 2;
    const int sc   = (tid & 3) * 16;

    uint4 kr0, kr1, vr0, vr1;
    auto gload = [&](int t0) {
        const unsigned short* kg = Kc + (size_t)(b * SS + t0 + srow) * EE + h * DHH + sc;
        kr0 = *(const uint4*)(kg);
        kr1 = *(const uint4*)(kg + 8);
        const unsigned short* vg = Vtc + (size_t)(b * EE + h * DHH + srow) * SS + t0 + sc;
        vr0 = *(const uint4*)(vg);
        vr1 = *(const uint4*)(vg + 8);
    };
    gload(0);

    for (int it = 0; it < ntiles; it++) {
        const int t0 = it * 64;
        __syncthreads();
        *(uint4*)(Ks + srow * LDK + sc)     = kr0;
        *(uint4*)(Ks + srow * LDK + sc + 8) = kr1;
        *(uint4*)(Vs + srow * LDV + sc)     = vr0;
        *(uint4*)(Vs + srow * LDV + sc + 8) = vr1;
        __syncthreads();

        if (it + 1 < ntiles) gload(t0 + 64);

        const bool full = (t0 + 64 <= nkeep);

        #pragma unroll
        for (int blk = 0; blk < 2; blk++) {
            f32x16 s;
            __builtin_amdgcn_s_setprio(1);
            {
                bf16x8 kf = *(const bf16x8*)(Ks + (blk * 32 + l32) * LDK + hi * 8);
                f32x16 z;
                #pragma unroll
                for (int r = 0; r < 16; r++) z[r] = 0.f;
                s = __builtin_amdgcn_mfma_f32_32x32x16_bf16(kf, qf[0], z, 0, 0, 0);
            }
            #pragma unroll
            for (int t = 1; t < 4; t++) {
                bf16x8 kf = *(const bf16x8*)(Ks + (blk * 32 + l32) * LDK + t * 16 + hi * 8);
                s = __builtin_amdgcn_mfma_f32_32x32x16_bf16(kf, qf[t], s, 0, 0, 0);
            }
            __builtin_amdgcn_s_setprio(0);

            float p[16];
            #pragma unroll
            for (int r = 0; r < 16; r++) p[r] = EXP2(s[r]);
            if (!full) {
                const int keyb = t0 + blk * 32 + 4 * hi;
                #pragma unroll
                for (int r = 0; r < 16; r++)
                    if (keyb + ((r & 3) + 8 * (r >> 2)) >= nkeep) p[r] = 0.f;
            }
            #pragma unroll
            for (int r = 0; r < 16; r += 4)
                lsum += ((p[r] + p[r + 1]) + (p[r + 2] + p[r + 3]));

            const unsigned int u0 = pk2bf(p[0],  p[1]);
            const unsigned int u1 = pk2bf(p[2],  p[3]);
            const unsigned int u2 = pk2bf(p[4],  p[5]);
            const unsigned int u3 = pk2bf(p[6],  p[7]);
            const unsigned int u4 = pk2bf(p[8],  p[9]);
            const unsigned int u5 = pk2bf(p[10], p[11]);
            const unsigned int u6 = pk2bf(p[12], p[13]);
            const unsigned int u7 = pk2bf(p[14], p[15]);
            const uint2v s02 = __builtin_amdgcn_permlane32_swap(u0, u2, false, false);
            const uint2v s13 = __builtin_amdgcn_permlane32_swap(u1, u3, false, false);
            const uint2v s46 = __builtin_amdgcn_permlane32_swap(u4, u6, false, false);
            const uint2v s57 = __builtin_amdgcn_permlane32_swap(u5, u7, false, false);

            union { unsigned int u[4]; bf16x8 v; } pa0, pa1;
            pa0.u[0] = s02.x; pa0.u[1] = s13.x; pa0.u[2] = s02.y; pa0.u[3] = s13.y;
            pa1.u[0] = s46.x; pa1.u[1] = s57.x; pa1.u[2] = s46.y; pa1.u[3] = s57.y;

            __builtin_amdgcn_s_setprio(1);
            #pragma unroll
            for (int kc = 0; kc < 2; kc++) {
                const bf16x8 pav = (kc == 0) ? pa0.v : pa1.v;
                #pragma unroll
                for (int dblk = 0; dblk < 2; dblk++) {
                    bf16x8 vf = *(const bf16x8*)(Vs + (dblk * 32 + l32) * LDV + blk * 32 + kc * 16 + hi * 8);
                    o_acc[dblk] = __builtin_amdgcn_mfma_f32_32x32x16_bf16(pav, vf, o_acc[dblk], 0, 0, 0);
                }
            }
            __builtin_amdgcn_s_setprio(0);
        }
    }

    {
        float ls = lsum;
        ls += __shfl_xor(ls, 32, 64);
        Lsum[wave][l32] = 1.0f / ls;
    }
    __builtin_amdgcn_s_waitcnt(0xC07F);

    #pragma unroll
    for (int r = 0; r < 16; r++) {
        const int qr = (r & 3) + 8 * (r >> 2) + 4 * hi;
        const float rl = Lsum[wave][qr];
        const size_t orow = (size_t)(b * SS + q0 + qr) * EE + h * DHH + l32;
        AO[orow]      = f2bf(o_acc[0][r] * rl);
        AO[orow + 32] = f2bf(o_acc[1][r] * rl);
    }
}

// ---------------------------------------------------------------------------
// Aliasing plan:
//   ws (40 MB):  [Wb 8 | Qb 8 | Kc 8 | Vtc 8 | AOb 8]
//   d_out: srcTab (16 KB) scratch -- dead before the out-GEMM overwrites.
// Pipeline (4 launches): cvt(weights+scan) -> proj GEMM (fused cvt+gather,
// V transposed epilogue) -> attn -> out GEMM.
// ---------------------------------------------------------------------------
extern "C" void kernel_launch(void* const* d_in, const int* in_sizes, int n_in,
                              void* d_out, int out_size, void* d_ws, size_t ws_size,
                              hipStream_t stream)
{
    (void)in_sizes; (void)n_in; (void)out_size; (void)ws_size;
    const float* queries = (const float*)d_in[0];
    const float* keys    = (const float*)d_in[1];
    const float* values  = (const float*)d_in[2];
    const int*   mask    = (const int*)d_in[3];
    const float* Wq      = (const float*)d_in[4];
    const float* Wk      = (const float*)d_in[5];
    const float* Wv      = (const float*)d_in[6];
    const float* Wo      = (const float*)d_in[7];
    const float* bo      = (const float*)d_in[8];

    const size_t NE = (size_t)BB * SS * EE;          // 4.19M elements
    const size_t WE = (size_t)EE * EE;               // 1.05M elements

    unsigned short* Wb  = (unsigned short*)d_ws;     // [0,8) MB
    unsigned short* Qb  = Wb + 4 * WE;               // [8,16)
    unsigned short* Kc  = Qb + NE;                   // [16,24)
    unsigned short* Vtc = Kc + NE;                   // [24,32)
    unsigned short* AOb = Vtc + NE;                  // [32,40)

    int* srcTab = (int*)d_out;                       // 16 KB scratch (dead by out-GEMM)

    const int M = BB * SS, N = EE, K = EE;
    // 1/sqrt(2048) * log2(e): softmax exp computed as exp2 of pre-scaled score
    const float qscale = 0.022097086912079608f * 1.4426950408889634f;

    cvt_kernel<<<dim3(512, 5), 256, 0, stream>>>(
        Wq, Wk, Wv, Wo, mask, Wb, srcTab);

    dim3 gproj(N / 128, M / 128, 3);
    gemm_xwt<128, 128, true, 1><<<gproj, 256, 0, stream>>>(
        nullptr, nullptr, nullptr,
        queries, keys, values, srcTab,
        Wb, Wb + WE, Wb + 2 * WE,
        (void*)Qb, (void*)Kc, (void*)Vtc, nullptr, M, N, K,
        qscale, 1.0f, 1.0f);

    attn_kernel<<<dim3(512), 256, 0, stream>>>(Qb, Kc, Vtc, mask, AOb);

    dim3 gout(N / 64, M / 128, 1);
    gemm_xwt<128, 64, false, 0><<<gout, 256, 0, stream>>>(
        AOb, AOb, AOb,
        nullptr, nullptr, nullptr, nullptr,
        Wb + 3 * WE, Wb + 3 * WE, Wb + 3 * WE,
        d_out, d_out, d_out, bo, M, N, K, 1.0f, 1.0f, 1.0f);
}